// Round 4
// baseline (472.920 us; speedup 1.0000x reference)
//
#include <hip/hip_runtime.h>
#include <math.h>

// GraphAttnModel: N=50000, E=800000, F=256, H=4, D=64.
// Pipeline:
//   1) convert feat + {Wq,Wk,Wv,Wskip} (+biases) to bf16 workspace copies
//   2) CSR-by-dst build (count / alloc / fill-src), scan-free wave atomics
//   3) fused bf16 MFMA GEMM (128x256 tile, global_load_lds staging,
//      LDS-transposed epilogue -> 16B coalesced stores)
//   4) one wave per dst node: MFMA-batched edge scores (16 edges/MFMA-chain),
//      no-max softmax (logits |e|<~1; softmax shift-invariant), fused
//      gate + LayerNorm + PReLU, f32 output.

typedef __attribute__((ext_vector_type(8))) short short8;   // 8 bf16 = 4 VGPRs
typedef __attribute__((ext_vector_type(4))) float floatx4;  // MFMA acc
typedef __attribute__((address_space(3))) void lds_void;
typedef __attribute__((address_space(1))) const void gbl_void;

__device__ inline unsigned short f2bf(float x) {            // RNE f32->bf16
    unsigned int u = __float_as_uint(x);
    u = (u + 0x7fffu + ((u >> 16) & 1u)) >> 16;
    return (unsigned short)u;
}
__device__ inline float bf2f(unsigned short u) {
    return __uint_as_float(((unsigned int)u) << 16);
}

// ---------------- converts ----------------

__global__ void convert_feat(const float* __restrict__ f, ushort* __restrict__ fb,
                             int n_elems, int total_pad) {
    int i = (blockIdx.x * blockDim.x + threadIdx.x) * 4;
    if (i >= total_pad) return;
    float4 v = (i < n_elems) ? *(const float4*)(f + i) : make_float4(0.f, 0.f, 0.f, 0.f);
    ushort4 u;
    u.x = f2bf(v.x); u.y = f2bf(v.y); u.z = f2bf(v.z); u.w = f2bf(v.w);
    *(ushort4*)(fb + i) = u;
}

__global__ void convert_w(const float* __restrict__ Wq, const float* __restrict__ Wk,
                          const float* __restrict__ Wv, const float* __restrict__ Wsk,
                          const float* __restrict__ bq, const float* __restrict__ bk,
                          const float* __restrict__ bv, const float* __restrict__ bsk,
                          ushort* __restrict__ Wcat, float* __restrict__ bcat) {
    int g = blockIdx.x * blockDim.x + threadIdx.x;
    if (g < 65536) {                       // 4*256*256 weight elems / 4
        int i = g * 4;
        int mat = i >> 16;
        int rem = i & 65535;
        const float* W = (mat == 0) ? Wq : (mat == 1) ? Wk : (mat == 2) ? Wv : Wsk;
        float4 v = *(const float4*)(W + rem);
        ushort4 u;
        u.x = f2bf(v.x); u.y = f2bf(v.y); u.z = f2bf(v.z); u.w = f2bf(v.w);
        *(ushort4*)(Wcat + i) = u;
    } else if (g < 65536 + 256) {          // 1024 bias elems / 4
        int o = (g - 65536) * 4;
        int mat = o >> 8;
        const float* b = (mat == 0) ? bq : (mat == 1) ? bk : (mat == 2) ? bv : bsk;
        *(float4*)(bcat + o) = *(const float4*)(b + (o & 255));
    }
}

// ---------------- CSR build ----------------

__global__ void init_kernel(int* counts, int* cursor, int n) {
    int i = blockIdx.x * blockDim.x + threadIdx.x;
    if (i < n) counts[i] = 0;
    if (i == 0) *cursor = 0;
}

__global__ void count_kernel(const int* __restrict__ dst, int* counts, int e) {
    int i = blockIdx.x * blockDim.x + threadIdx.x;
    if (i < e) atomicAdd(&counts[dst[i]], 1);
}

__global__ void alloc_kernel(const int* __restrict__ counts, int* start, int* cur,
                             int* cursor, int n) {
    int i = blockIdx.x * blockDim.x + threadIdx.x;
    int lane = threadIdx.x & 63;
    int c = (i < n) ? counts[i] : 0;
    int incl = c;
#pragma unroll
    for (int d = 1; d < 64; d <<= 1) {
        int t = __shfl_up(incl, d);
        if (lane >= d) incl += t;
    }
    int waveTot = __shfl(incl, 63);
    int base = 0;
    if (lane == 63) base = atomicAdd(cursor, waveTot);
    base = __shfl(base, 63);
    if (i < n) {
        int s = base + incl - c;
        start[i] = s;
        cur[i] = s;
    }
}

// store SRC node id directly in the slot: node phase needs only src ids
__global__ void fill_kernel(const int* __restrict__ dst, const int* __restrict__ src,
                            int* cur, int* srclist, int e) {
    int i = blockIdx.x * blockDim.x + threadIdx.x;
    if (i < e) {
        int pos = atomicAdd(&cur[dst[i]], 1);
        srclist[pos] = src[i];
    }
}

// ---------------- fused bf16 MFMA projection GEMM ----------------
// C[m][o] = sum_k featb[m][k] * Wcat[o][k] + bcat[o],  m<50048(pad), o<1024.
// Block: 512 thr = 8 waves; tile 128m x 256n; wave tile 64x64 (4x4 MFMA).
// blockIdx.y selects the output matrix (q/k/v/skip) -> uniform outp.
// Epilogue: per-wave LDS transpose (stride 72 pad) -> 16B global stores.
__global__ __launch_bounds__(512) void mfma_gemm(
    const ushort* __restrict__ featb, const ushort* __restrict__ Wcat,
    const float* __restrict__ bcat,
    ushort* __restrict__ qb, ushort* __restrict__ kb,
    ushort* __restrict__ vb, ushort* __restrict__ sb, int n)
{
    __shared__ ushort lds[128 * 32 + 256 * 32];   // 24 KB: At(8K) + Bt(16K)
    ushort* At = lds;
    ushort* Bt = lds + 128 * 32;
    int tid = threadIdx.x;
    int lane = tid & 63;
    int wv = tid >> 6;               // 0..7
    int mBase = blockIdx.x * 128;
    int nBlk = blockIdx.y * 256;     // one output matrix per y-block
    int mQuad = (wv & 1) * 64;
    int nQuad = (wv >> 1) * 64;

    floatx4 zero = {0.f, 0.f, 0.f, 0.f};
    floatx4 acc[4][4];
#pragma unroll
    for (int i = 0; i < 4; ++i)
#pragma unroll
        for (int j = 0; j < 4; ++j) acc[i][j] = zero;

    int rsel = lane & 15;
    int ksel = (lane >> 4) * 8;
    int lrow = lane >> 2;            // 0..15
    int lcol = (lane & 3) * 8;       // ushort offset 0,8,16,24

    for (int k0 = 0; k0 < 256; k0 += 32) {
        // A: 128x32; wave w stages rows 16w..16w+15 (one 1 KB issue)
        {
            int row = 16 * wv + lrow;
            const ushort* gp = featb + (size_t)(mBase + row) * 256 + k0 + lcol;
            __builtin_amdgcn_global_load_lds((gbl_void*)gp, (lds_void*)&At[16 * wv * 32], 16, 0, 0);
        }
        // B: 256x32; wave w stages rows 32w..32w+31 (two issues)
#pragma unroll
        for (int r = 0; r < 2; ++r) {
            int row = 32 * wv + 16 * r + lrow;
            const ushort* gp = Wcat + (size_t)(nBlk + row) * 256 + k0 + lcol;
            __builtin_amdgcn_global_load_lds((gbl_void*)gp, (lds_void*)&Bt[(32 * wv + 16 * r) * 32], 16, 0, 0);
        }
        __syncthreads();
        short8 af[4], bf[4];
#pragma unroll
        for (int i = 0; i < 4; ++i)
            af[i] = *(const short8*)&At[(mQuad + 16 * i + rsel) * 32 + ksel];
#pragma unroll
        for (int j = 0; j < 4; ++j)
            bf[j] = *(const short8*)&Bt[(nQuad + 16 * j + rsel) * 32 + ksel];
#pragma unroll
        for (int i = 0; i < 4; ++i)
#pragma unroll
            for (int j = 0; j < 4; ++j)
                acc[i][j] = __builtin_amdgcn_mfma_f32_16x16x32_bf16(af[i], bf[j], acc[i][j], 0, 0, 0);
        __syncthreads();
    }

    ushort* outp = (blockIdx.y == 0) ? qb : (blockIdx.y == 1) ? kb
                 : (blockIdx.y == 2) ? vb : sb;

    // wave-private transpose buffer: 16 rows x 72 ushorts (pad) = 2304 B
    ushort* tb = lds + wv * 1152;
    int colq = lane & 15;
    int rowq4 = (lane >> 4) * 4;
    float bj[4];
#pragma unroll
    for (int j = 0; j < 4; ++j) bj[j] = bcat[nBlk + nQuad + 16 * j + colq];

    int rr = lane >> 2;              // 0..15
    int cc = (lane & 3) * 16;        // 0,16,32,48
#pragma unroll
    for (int i = 0; i < 4; ++i) {
#pragma unroll
        for (int j = 0; j < 4; ++j) {
            int c_loc = 16 * j + colq;
#pragma unroll
            for (int r = 0; r < 4; ++r)
                tb[(rowq4 + r) * 72 + c_loc] = f2bf(acc[i][j][r] + bj[j]);
        }
        __syncthreads();             // forces LDS write->read ordering
        short8 x0 = *(const short8*)&tb[rr * 72 + cc];
        short8 x1 = *(const short8*)&tb[rr * 72 + cc + 8];
        int m = mBase + mQuad + 16 * i + rr;
        if (m < n) {
            ushort* gp = outp + (size_t)m * 256 + nQuad + cc;
            *(short8*)gp = x0;
            *(short8*)(gp + 8) = x1;
        }
        __syncthreads();             // protect tb before next i overwrites
    }
}

// ---------------- per-node attention + epilogue ----------------
// One wave per dst node. Scores via MFMA: per 16-edge batch,
// A[m=edge][k]=q[src_m][k], B[n=head][k]=(k in head n)?k_dst[k]:0, K=256
// -> D[edge][head] with no shuffles. Weights w=exp(score/8) broadcast via
// one bpermute per edge; V aggregated per 16-lane head-group.
__global__ __launch_bounds__(256) void node_kernel(
    const ushort* __restrict__ qb, const ushort* __restrict__ kb,
    const ushort* __restrict__ vb, const ushort* __restrict__ sbuf,
    const int* __restrict__ srclist, const int* __restrict__ start,
    const int* __restrict__ counts,
    const float* __restrict__ Wg, const float* __restrict__ bg,
    const float* __restrict__ lnw, const float* __restrict__ lnb,
    const float* __restrict__ pa,
    float* __restrict__ out, int n, int E)
{
    int wvi = threadIdx.x >> 6;
    int lane = threadIdx.x & 63;
    int node = blockIdx.x * 4 + wvi;
    if (node >= n) return;

    int hd = lane >> 4;                         // head group 0..3
    int f0 = hd * 64 + (lane & 15) * 4;         // 4 consecutive feats (V/epilogue)
    int ksub = hd * 16;                         // byte offset of this lane's k-chunk

    // B-frags from k[node], masked per head (8 chunks cover K=256)
    short8 z8 = {0, 0, 0, 0, 0, 0, 0, 0};
    short8 bfrag[8];
    {
        const char* krow = (const char*)kb + (unsigned)node * 512u + ksub;
#pragma unroll
        for (int c = 0; c < 8; ++c) {
            short8 kv = *(const short8*)(krow + c * 64);
            int khead = (4 * c + hd) >> 3;      // head of k-range [32c+8hd, +8)
            bfrag[c] = (khead == (lane & 15)) ? kv : z8;
        }
    }

    float lsum = 0.f, a0 = 0.f, a1 = 0.f, a2 = 0.f, a3 = 0.f;
    floatx4 zero = {0.f, 0.f, 0.f, 0.f};

    int sidx = start[node], cnt = counts[node];

    for (int base = 0; base < cnt; base += 64) {
        int m = min(64, cnt - base);
        int batch = srclist[min(sidx + base + lane, E - 1)];
        for (int b = 0; b < 4 && b * 16 < m; ++b) {
            int mb = min(16, m - b * 16);
            // A-frags: lane loads q row of edge (lane&15), its k-chunk
            int sA = __shfl(batch, b * 16 + (lane & 15));
            const char* qrow = (const char*)qb + (unsigned)sA * 512u + ksub;
            short8 af[8];
#pragma unroll
            for (int c = 0; c < 8; ++c)
                af[c] = *(const short8*)(qrow + c * 64);
            floatx4 s0 = zero, s1 = zero;
#pragma unroll
            for (int c = 0; c < 8; c += 2) {
                s0 = __builtin_amdgcn_mfma_f32_16x16x32_bf16(af[c], bfrag[c], s0, 0, 0, 0);
                s1 = __builtin_amdgcn_mfma_f32_16x16x32_bf16(af[c + 1], bfrag[c + 1], s1, 0, 0, 0);
            }
            float wr[4];
#pragma unroll
            for (int r = 0; r < 4; ++r)
                wr[r] = __expf((s0[r] + s1[r]) * 0.125f);
            // V aggregation: per edge, broadcast w + src, gather v row
#pragma unroll
            for (int j = 0; j < 16; ++j) {
                if (j >= mb) break;
                float wj = __shfl(wr[j & 3], ((j >> 2) << 4) + hd);
                int sj = __shfl(batch, b * 16 + j);
                const char* vrow = (const char*)vb + (unsigned)sj * 512u + f0 * 2;
                ushort4 vu = *(const ushort4*)vrow;
                lsum += wj;
                a0 += wj * bf2f(vu.x);
                a1 += wj * bf2f(vu.y);
                a2 += wj * bf2f(vu.z);
                a3 += wj * bf2f(vu.w);
            }
        }
    }
    float inv = (lsum > 0.f) ? 1.f / lsum : 0.f;
    float r0 = a0 * inv, r1 = a1 * inv, r2 = a2 * inv, r3 = a3 * inv;

    ushort4 su = *(const ushort4*)((const char*)sbuf + (unsigned)node * 512u + f0 * 2);
    float s0f = bf2f(su.x), s1f = bf2f(su.y), s2f = bf2f(su.z), s3f = bf2f(su.w);

    float4 w0v = *(const float4*)(Wg + f0);
    float4 w1v = *(const float4*)(Wg + 256 + f0);
    float4 w2v = *(const float4*)(Wg + 512 + f0);
    float z = w0v.x * s0f + w0v.y * s1f + w0v.z * s2f + w0v.w * s3f
            + w1v.x * r0 + w1v.y * r1 + w1v.z * r2 + w1v.w * r3
            + w2v.x * (s0f - r0) + w2v.y * (s1f - r1) + w2v.z * (s2f - r2) + w2v.w * (s3f - r3);
#pragma unroll
    for (int d = 32; d >= 1; d >>= 1) z += __shfl_xor(z, d);
    z += bg[0];
    float g = 1.f / (1.f + __expf(-z));

    float y0 = g * s0f + (1.f - g) * r0;
    float y1 = g * s1f + (1.f - g) * r1;
    float y2 = g * s2f + (1.f - g) * r2;
    float y3 = g * s3f + (1.f - g) * r3;

    float sum = y0 + y1 + y2 + y3;
#pragma unroll
    for (int d = 32; d >= 1; d >>= 1) sum += __shfl_xor(sum, d);
    float mu = sum * (1.f / 256.f);
    float d0 = y0 - mu, d1 = y1 - mu, d2 = y2 - mu, d3 = y3 - mu;
    float sq = d0 * d0 + d1 * d1 + d2 * d2 + d3 * d3;
#pragma unroll
    for (int d = 32; d >= 1; d >>= 1) sq += __shfl_xor(sq, d);
    float rstd = rsqrtf(sq * (1.f / 256.f) + 1e-5f);

    float4 lw = *(const float4*)(lnw + f0);
    float4 lb = *(const float4*)(lnb + f0);
    float o0 = d0 * rstd * lw.x + lb.x;
    float o1 = d1 * rstd * lw.y + lb.y;
    float o2 = d2 * rstd * lw.z + lb.z;
    float o3 = d3 * rstd * lw.w + lb.w;
    float ap = pa[0];
    o0 = (o0 >= 0.f) ? o0 : ap * o0;
    o1 = (o1 >= 0.f) ? o1 : ap * o1;
    o2 = (o2 >= 0.f) ? o2 : ap * o2;
    o3 = (o3 >= 0.f) ? o3 : ap * o3;

    *(float4*)(out + (size_t)node * 256 + f0) = make_float4(o0, o1, o2, o3);
}

// ---------------- launch ----------------

extern "C" void kernel_launch(void* const* d_in, const int* in_sizes, int n_in,
                              void* d_out, int out_size, void* d_ws, size_t ws_size,
                              hipStream_t stream)
{
    const float* feat = (const float*)d_in[0];
    const int* src    = (const int*)d_in[1];
    const int* dst    = (const int*)d_in[2];
    const float* Wq   = (const float*)d_in[3];
    const float* bq   = (const float*)d_in[4];
    const float* Wk   = (const float*)d_in[5];
    const float* bk   = (const float*)d_in[6];
    const float* Wv   = (const float*)d_in[7];
    const float* bv   = (const float*)d_in[8];
    const float* Wsk  = (const float*)d_in[9];
    const float* bsk  = (const float*)d_in[10];
    const float* Wg   = (const float*)d_in[11];
    const float* bg   = (const float*)d_in[12];
    const float* lnw  = (const float*)d_in[13];
    const float* lnb  = (const float*)d_in[14];
    const float* pa   = (const float*)d_in[15];

    int N = in_sizes[0] / 256;
    int E = in_sizes[1];
    float* out = (float*)d_out;

    int Mtiles = (N + 127) / 128;
    int Npad = Mtiles * 128;

    char* ws = (char*)d_ws;
    size_t off = 0;
    auto alloc = [&](size_t bytes) { char* p = ws + off; off = (off + bytes + 255) & ~(size_t)255; return p; };
    ushort* featb  = (ushort*)alloc((size_t)Npad * 256 * 2);
    ushort* Wcat   = (ushort*)alloc(1024 * 256 * 2);
    float*  bcat   = (float*) alloc(1024 * 4);
    ushort* qb     = (ushort*)alloc((size_t)N * 256 * 2);
    ushort* kb     = (ushort*)alloc((size_t)N * 256 * 2);
    ushort* vb     = (ushort*)alloc((size_t)N * 256 * 2);
    ushort* sb     = (ushort*)alloc((size_t)N * 256 * 2);
    int* counts    = (int*)alloc((size_t)N * 4);
    int* startv    = (int*)alloc((size_t)N * 4);
    int* cur       = (int*)alloc((size_t)N * 4);
    int* cursor    = (int*)alloc(4);
    int* srclist   = (int*)alloc((size_t)E * 4);

    int totPad = Npad * 256;
    convert_feat<<<(totPad / 4 + 255) / 256, 256, 0, stream>>>(feat, featb, N * 256, totPad);
    convert_w<<<(65536 + 256 + 255) / 256, 256, 0, stream>>>(Wq, Wk, Wv, Wsk, bq, bk, bv, bsk, Wcat, bcat);

    init_kernel<<<(N + 255) / 256, 256, 0, stream>>>(counts, cursor, N);
    count_kernel<<<(E + 255) / 256, 256, 0, stream>>>(dst, counts, E);
    alloc_kernel<<<(N + 255) / 256, 256, 0, stream>>>(counts, startv, cur, cursor, N);
    fill_kernel<<<(E + 255) / 256, 256, 0, stream>>>(dst, src, cur, srclist, E);

    dim3 gg(Mtiles, 4);
    mfma_gemm<<<gg, 512, 0, stream>>>(featb, Wcat, bcat, qb, kb, vb, sb, N);

    node_kernel<<<(N + 3) / 4, 256, 0, stream>>>(qb, kb, vb, sb, srclist, startv, counts,
                                                 Wg, bg, lnw, lnb, pa, out, N, E);
}

// Round 5
// 411.089 us; speedup vs baseline: 1.1504x; 1.1504x over previous
//
#include <hip/hip_runtime.h>
#include <math.h>

// GraphAttnModel: N=50000, E=800000, F=256, H=4, D=64.
// Pipeline:
//   1) prep: convert feat+weights+biases to bf16 ws copies, zero CSR counters
//   2) CSR-by-dst build (count / alloc / fill-src), scan-free wave atomics
//   3) fused bf16 MFMA GEMM (128x256 tile, global_load_lds staging).
//      MFMA operands SWAPPED -> each lane holds 4 consecutive output cols of
//      one row -> packed 8B bf16 stores (16/lane instead of 64 scalar).
//   4) one wave per dst node: no-max softmax edge attention (logits |e|<~1;
//      softmax shift-invariant) + gate + LayerNorm + PReLU, f32 output.

typedef __attribute__((ext_vector_type(8))) short short8;   // 8 bf16 = 4 VGPRs
typedef __attribute__((ext_vector_type(4))) float floatx4;  // MFMA acc
typedef __attribute__((address_space(3))) void lds_void;
typedef __attribute__((address_space(1))) const void gbl_void;

__device__ inline unsigned short f2bf(float x) {            // RNE f32->bf16
    unsigned int u = __float_as_uint(x);
    u = (u + 0x7fffu + ((u >> 16) & 1u)) >> 16;
    return (unsigned short)u;
}
__device__ inline float bf2f(unsigned short u) {
    return __uint_as_float(((unsigned int)u) << 16);
}

// ---------------- prep: converts + CSR zero ----------------
// region A: feat -> bf16 (Npad*256 elems, /4)
// region B: Wq|Wk|Wv|Wsk -> Wcat bf16 (262144 elems, /4)
// region C: biases -> bcat f32 (1024, /4)
// region D: counts zero (N) + cursor
__global__ void prep_kernel(const float* __restrict__ f, ushort* __restrict__ fb,
                            int n_elems, int total_pad,
                            const float* __restrict__ Wq, const float* __restrict__ Wk,
                            const float* __restrict__ Wv, const float* __restrict__ Wsk,
                            const float* __restrict__ bq, const float* __restrict__ bk,
                            const float* __restrict__ bv, const float* __restrict__ bsk,
                            ushort* __restrict__ Wcat, float* __restrict__ bcat,
                            int* __restrict__ counts, int* __restrict__ cursor, int n)
{
    int g = blockIdx.x * blockDim.x + threadIdx.x;
    int featQ = total_pad >> 2;               // feat quads
    if (g < featQ) {
        int i = g * 4;
        float4 v = (i < n_elems) ? *(const float4*)(f + i) : make_float4(0.f, 0.f, 0.f, 0.f);
        ushort4 u;
        u.x = f2bf(v.x); u.y = f2bf(v.y); u.z = f2bf(v.z); u.w = f2bf(v.w);
        *(ushort4*)(fb + i) = u;
        return;
    }
    int g2 = g - featQ;
    if (g2 < 65536) {                         // weights: 262144/4
        int i = g2 * 4;
        int mat = i >> 16;
        int rem = i & 65535;
        const float* W = (mat == 0) ? Wq : (mat == 1) ? Wk : (mat == 2) ? Wv : Wsk;
        float4 v = *(const float4*)(W + rem);
        ushort4 u;
        u.x = f2bf(v.x); u.y = f2bf(v.y); u.z = f2bf(v.z); u.w = f2bf(v.w);
        *(ushort4*)(Wcat + i) = u;
        return;
    }
    int g3 = g2 - 65536;
    if (g3 < 256) {                           // biases: 1024/4
        int o = g3 * 4;
        int mat = o >> 8;
        const float* b = (mat == 0) ? bq : (mat == 1) ? bk : (mat == 2) ? bv : bsk;
        *(float4*)(bcat + o) = *(const float4*)(b + (o & 255));
        return;
    }
    int g4 = g3 - 256;
    if (g4 < n) counts[g4] = 0;
    if (g4 == 0) *cursor = 0;
}

// ---------------- CSR build ----------------

__global__ void count_kernel(const int* __restrict__ dst, int* counts, int e) {
    int i = blockIdx.x * blockDim.x + threadIdx.x;
    if (i < e) atomicAdd(&counts[dst[i]], 1);
}

__global__ void alloc_kernel(const int* __restrict__ counts, int* start, int* cur,
                             int* cursor, int n) {
    int i = blockIdx.x * blockDim.x + threadIdx.x;
    int lane = threadIdx.x & 63;
    int c = (i < n) ? counts[i] : 0;
    int incl = c;
#pragma unroll
    for (int d = 1; d < 64; d <<= 1) {
        int t = __shfl_up(incl, d);
        if (lane >= d) incl += t;
    }
    int waveTot = __shfl(incl, 63);
    int base = 0;
    if (lane == 63) base = atomicAdd(cursor, waveTot);
    base = __shfl(base, 63);
    if (i < n) {
        int s = base + incl - c;
        start[i] = s;
        cur[i] = s;
    }
}

// store SRC node id directly in the slot: node phase needs only src ids
__global__ void fill_kernel(const int* __restrict__ dst, const int* __restrict__ src,
                            int* cur, int* srclist, int e) {
    int i = blockIdx.x * blockDim.x + threadIdx.x;
    if (i < e) {
        int pos = atomicAdd(&cur[dst[i]], 1);
        srclist[pos] = src[i];
    }
}

// ---------------- fused bf16 MFMA projection GEMM ----------------
// C[m][o] = sum_k featb[m][k] * Wcat[o][k] + bcat[o],  m<50048(pad), o<1024.
// Block: 512 thr = 8 waves; tile 128m x 256n; wave tile 64x64 (4x4 MFMA).
// blockIdx.y selects the output matrix (q/k/v/skip) -> uniform outp.
// MFMA called as mfma(bf, af, acc): D[n_local][m_local] with
// m_local = lane&15 (one row per lane), n_local = (lane>>4)*4 + reg
// (4 consecutive cols) -> pack 4 bf16, one 8B store per (mt,nt).
__global__ __launch_bounds__(512) void mfma_gemm(
    const ushort* __restrict__ featb, const ushort* __restrict__ Wcat,
    const float* __restrict__ bcat,
    ushort* __restrict__ qb, ushort* __restrict__ kb,
    ushort* __restrict__ vb, ushort* __restrict__ sb, int n)
{
    __shared__ ushort At[128 * 32];  // 8 KB
    __shared__ ushort Bt[256 * 32];  // 16 KB
    int tid = threadIdx.x;
    int lane = tid & 63;
    int wv = tid >> 6;               // 0..7
    int mBase = blockIdx.x * 128;
    int nBlk = blockIdx.y * 256;     // one output matrix per y-block
    int mQuad = (wv & 1) * 64;
    int nQuad = (wv >> 1) * 64;

    floatx4 zero = {0.f, 0.f, 0.f, 0.f};
    floatx4 acc[4][4];               // [m-tile][n-tile]
#pragma unroll
    for (int i = 0; i < 4; ++i)
#pragma unroll
        for (int j = 0; j < 4; ++j) acc[i][j] = zero;

    int rsel = lane & 15;
    int ksel = (lane >> 4) * 8;
    int lrow = lane >> 2;            // 0..15
    int lcol = (lane & 3) * 8;       // ushort offset 0,8,16,24

    for (int k0 = 0; k0 < 256; k0 += 32) {
        // A: 128x32; wave w stages rows 16w..16w+15 (one 1 KB issue)
        {
            int row = 16 * wv + lrow;
            const ushort* gp = featb + (size_t)(mBase + row) * 256 + k0 + lcol;
            __builtin_amdgcn_global_load_lds((gbl_void*)gp, (lds_void*)&At[16 * wv * 32], 16, 0, 0);
        }
        // B: 256x32; wave w stages rows 32w..32w+31 (two issues)
#pragma unroll
        for (int r = 0; r < 2; ++r) {
            int row = 32 * wv + 16 * r + lrow;
            const ushort* gp = Wcat + (size_t)(nBlk + row) * 256 + k0 + lcol;
            __builtin_amdgcn_global_load_lds((gbl_void*)gp, (lds_void*)&Bt[(32 * wv + 16 * r) * 32], 16, 0, 0);
        }
        __syncthreads();
        short8 af[4], bf[4];
#pragma unroll
        for (int i = 0; i < 4; ++i)
            af[i] = *(const short8*)&At[(mQuad + 16 * i + rsel) * 32 + ksel];
#pragma unroll
        for (int j = 0; j < 4; ++j)
            bf[j] = *(const short8*)&Bt[(nQuad + 16 * j + rsel) * 32 + ksel];
#pragma unroll
        for (int i = 0; i < 4; ++i)
#pragma unroll
            for (int j = 0; j < 4; ++j)
                acc[i][j] = __builtin_amdgcn_mfma_f32_16x16x32_bf16(bf[j], af[i], acc[i][j], 0, 0, 0);
        __syncthreads();
    }

    ushort* outp = (blockIdx.y == 0) ? qb : (blockIdx.y == 1) ? kb
                 : (blockIdx.y == 2) ? vb : sb;

    int rowq4 = (lane >> 4) * 4;     // n_local base of this lane's 4 cols
    float4 bias[4];
#pragma unroll
    for (int nt = 0; nt < 4; ++nt)
        bias[nt] = *(const float4*)(bcat + nBlk + nQuad + 16 * nt + rowq4);

#pragma unroll
    for (int mt = 0; mt < 4; ++mt) {
        int m = mBase + mQuad + 16 * mt + (lane & 15);
        if (m < n) {
            ushort* rowp = outp + (size_t)m * 256 + nQuad + rowq4;
#pragma unroll
            for (int nt = 0; nt < 4; ++nt) {
                uint lo = (uint)f2bf(acc[mt][nt][0] + bias[nt].x)
                        | ((uint)f2bf(acc[mt][nt][1] + bias[nt].y) << 16);
                uint hi = (uint)f2bf(acc[mt][nt][2] + bias[nt].z)
                        | ((uint)f2bf(acc[mt][nt][3] + bias[nt].w) << 16);
                uint2 pk = make_uint2(lo, hi);
                *(uint2*)(rowp + 16 * nt) = pk;
            }
        }
    }
}

// ---------------- per-node attention + epilogue ----------------
// One wave per dst node; 16-lane group g = head g; lane owns 4 consecutive
// features. Softmax without max-subtraction (shift-invariant; logits tiny).
// 2-edge unroll with split accumulators; src ids batched 64-at-a-time.
__global__ __launch_bounds__(256) void node_kernel(
    const ushort* __restrict__ qb, const ushort* __restrict__ kb,
    const ushort* __restrict__ vb, const ushort* __restrict__ sbuf,
    const int* __restrict__ srclist, const int* __restrict__ start,
    const int* __restrict__ counts,
    const float* __restrict__ Wg, const float* __restrict__ bg,
    const float* __restrict__ lnw, const float* __restrict__ lnb,
    const float* __restrict__ pa,
    float* __restrict__ out, int n, int E)
{
    int wvi = threadIdx.x >> 6;
    int lane = threadIdx.x & 63;
    int node = blockIdx.x * 4 + wvi;
    if (node >= n) return;

    int f0 = (lane >> 4) * 64 + (lane & 15) * 4;

    ushort4 ku = *(const ushort4*)(kb + (size_t)node * 256 + f0);
    float k0 = bf2f(ku.x), k1 = bf2f(ku.y), k2 = bf2f(ku.z), k3 = bf2f(ku.w);

    float lA = 0.f, a0 = 0.f, a1 = 0.f, a2 = 0.f, a3 = 0.f;
    float lB = 0.f, b0 = 0.f, b1 = 0.f, b2 = 0.f, b3 = 0.f;

    int sidx = start[node], cnt = counts[node];

    for (int base = 0; base < cnt; base += 64) {
        int m = min(64, cnt - base);
        int gi = sidx + base + lane;
        int batch = srclist[min(gi, E - 1)];
        int j = 0;
        for (; j + 1 < m; j += 2) {
            int s0i = __shfl(batch, j);
            int s1i = __shfl(batch, j + 1);
            ushort4 qu0 = *(const ushort4*)(qb + (size_t)s0i * 256 + f0);
            ushort4 vu0 = *(const ushort4*)(vb + (size_t)s0i * 256 + f0);
            ushort4 qu1 = *(const ushort4*)(qb + (size_t)s1i * 256 + f0);
            ushort4 vu1 = *(const ushort4*)(vb + (size_t)s1i * 256 + f0);
            float p0 = bf2f(qu0.x) * k0 + bf2f(qu0.y) * k1 + bf2f(qu0.z) * k2 + bf2f(qu0.w) * k3;
            float p1 = bf2f(qu1.x) * k0 + bf2f(qu1.y) * k1 + bf2f(qu1.z) * k2 + bf2f(qu1.w) * k3;
            p0 += __shfl_xor(p0, 1);  p1 += __shfl_xor(p1, 1);
            p0 += __shfl_xor(p0, 2);  p1 += __shfl_xor(p1, 2);
            p0 += __shfl_xor(p0, 4);  p1 += __shfl_xor(p1, 4);
            p0 += __shfl_xor(p0, 8);  p1 += __shfl_xor(p1, 8);
            float w0 = __expf(p0 * 0.125f);
            float w1 = __expf(p1 * 0.125f);
            lA += w0;
            a0 += w0 * bf2f(vu0.x); a1 += w0 * bf2f(vu0.y);
            a2 += w0 * bf2f(vu0.z); a3 += w0 * bf2f(vu0.w);
            lB += w1;
            b0 += w1 * bf2f(vu1.x); b1 += w1 * bf2f(vu1.y);
            b2 += w1 * bf2f(vu1.z); b3 += w1 * bf2f(vu1.w);
        }
        if (j < m) {
            int s0i = __shfl(batch, j);
            ushort4 qu0 = *(const ushort4*)(qb + (size_t)s0i * 256 + f0);
            ushort4 vu0 = *(const ushort4*)(vb + (size_t)s0i * 256 + f0);
            float p0 = bf2f(qu0.x) * k0 + bf2f(qu0.y) * k1 + bf2f(qu0.z) * k2 + bf2f(qu0.w) * k3;
            p0 += __shfl_xor(p0, 1);
            p0 += __shfl_xor(p0, 2);
            p0 += __shfl_xor(p0, 4);
            p0 += __shfl_xor(p0, 8);
            float w0 = __expf(p0 * 0.125f);
            lA += w0;
            a0 += w0 * bf2f(vu0.x); a1 += w0 * bf2f(vu0.y);
            a2 += w0 * bf2f(vu0.z); a3 += w0 * bf2f(vu0.w);
        }
    }
    float lsum = lA + lB;
    float inv = (lsum > 0.f) ? 1.f / lsum : 0.f;
    float r0 = (a0 + b0) * inv, r1 = (a1 + b1) * inv;
    float r2 = (a2 + b2) * inv, r3 = (a3 + b3) * inv;

    ushort4 su = *(const ushort4*)(sbuf + (size_t)node * 256 + f0);
    float s0 = bf2f(su.x), s1 = bf2f(su.y), s2 = bf2f(su.z), s3 = bf2f(su.w);

    float4 w0v = *(const float4*)(Wg + f0);
    float4 w1v = *(const float4*)(Wg + 256 + f0);
    float4 w2v = *(const float4*)(Wg + 512 + f0);
    float z = w0v.x * s0 + w0v.y * s1 + w0v.z * s2 + w0v.w * s3
            + w1v.x * r0 + w1v.y * r1 + w1v.z * r2 + w1v.w * r3
            + w2v.x * (s0 - r0) + w2v.y * (s1 - r1) + w2v.z * (s2 - r2) + w2v.w * (s3 - r3);
#pragma unroll
    for (int d = 32; d >= 1; d >>= 1) z += __shfl_xor(z, d);
    z += bg[0];
    float g = 1.f / (1.f + __expf(-z));

    float y0 = g * s0 + (1.f - g) * r0;
    float y1 = g * s1 + (1.f - g) * r1;
    float y2 = g * s2 + (1.f - g) * r2;
    float y3 = g * s3 + (1.f - g) * r3;

    float sum = y0 + y1 + y2 + y3;
#pragma unroll
    for (int d = 32; d >= 1; d >>= 1) sum += __shfl_xor(sum, d);
    float mu = sum * (1.f / 256.f);
    float d0 = y0 - mu, d1 = y1 - mu, d2 = y2 - mu, d3 = y3 - mu;
    float sq = d0 * d0 + d1 * d1 + d2 * d2 + d3 * d3;
#pragma unroll
    for (int d = 32; d >= 1; d >>= 1) sq += __shfl_xor(sq, d);
    float rstd = rsqrtf(sq * (1.f / 256.f) + 1e-5f);

    float4 lw = *(const float4*)(lnw + f0);
    float4 lb = *(const float4*)(lnb + f0);
    float o0 = d0 * rstd * lw.x + lb.x;
    float o1 = d1 * rstd * lw.y + lb.y;
    float o2 = d2 * rstd * lw.z + lb.z;
    float o3 = d3 * rstd * lw.w + lb.w;
    float ap = pa[0];
    o0 = (o0 >= 0.f) ? o0 : ap * o0;
    o1 = (o1 >= 0.f) ? o1 : ap * o1;
    o2 = (o2 >= 0.f) ? o2 : ap * o2;
    o3 = (o3 >= 0.f) ? o3 : ap * o3;

    *(float4*)(out + (size_t)node * 256 + f0) = make_float4(o0, o1, o2, o3);
}

// ---------------- launch ----------------

extern "C" void kernel_launch(void* const* d_in, const int* in_sizes, int n_in,
                              void* d_out, int out_size, void* d_ws, size_t ws_size,
                              hipStream_t stream)
{
    const float* feat = (const float*)d_in[0];
    const int* src    = (const int*)d_in[1];
    const int* dst    = (const int*)d_in[2];
    const float* Wq   = (const float*)d_in[3];
    const float* bq   = (const float*)d_in[4];
    const float* Wk   = (const float*)d_in[5];
    const float* bk   = (const float*)d_in[6];
    const float* Wv   = (const float*)d_in[7];
    const float* bv   = (const float*)d_in[8];
    const float* Wsk  = (const float*)d_in[9];
    const float* bsk  = (const float*)d_in[10];
    const float* Wg   = (const float*)d_in[11];
    const float* bg   = (const float*)d_in[12];
    const float* lnw  = (const float*)d_in[13];
    const float* lnb  = (const float*)d_in[14];
    const float* pa   = (const float*)d_in[15];

    int N = in_sizes[0] / 256;
    int E = in_sizes[1];
    float* out = (float*)d_out;

    int Mtiles = (N + 127) / 128;
    int Npad = Mtiles * 128;

    char* ws = (char*)d_ws;
    size_t off = 0;
    auto alloc = [&](size_t bytes) { char* p = ws + off; off = (off + bytes + 255) & ~(size_t)255; return p; };
    ushort* featb  = (ushort*)alloc((size_t)Npad * 256 * 2);
    ushort* Wcat   = (ushort*)alloc(1024 * 256 * 2);
    float*  bcat   = (float*) alloc(1024 * 4);
    ushort* qb     = (ushort*)alloc((size_t)N * 256 * 2);
    ushort* kb     = (ushort*)alloc((size_t)N * 256 * 2);
    ushort* vb     = (ushort*)alloc((size_t)N * 256 * 2);
    ushort* sb     = (ushort*)alloc((size_t)N * 256 * 2);
    int* counts    = (int*)alloc((size_t)N * 4);
    int* startv    = (int*)alloc((size_t)N * 4);
    int* cur       = (int*)alloc((size_t)N * 4);
    int* cursor    = (int*)alloc(4);
    int* srclist   = (int*)alloc((size_t)E * 4);

    int totPad = Npad * 256;
    int prepThreads = totPad / 4 + 65536 + 256 + N;
    prep_kernel<<<(prepThreads + 255) / 256, 256, 0, stream>>>(
        feat, featb, N * 256, totPad, Wq, Wk, Wv, Wsk, bq, bk, bv, bsk,
        Wcat, bcat, counts, cursor, N);

    count_kernel<<<(E + 255) / 256, 256, 0, stream>>>(dst, counts, E);
    alloc_kernel<<<(N + 255) / 256, 256, 0, stream>>>(counts, startv, cur, cursor, N);
    fill_kernel<<<(E + 255) / 256, 256, 0, stream>>>(dst, src, cur, srclist, E);

    dim3 gg(Mtiles, 4);
    mfma_gemm<<<gg, 512, 0, stream>>>(featb, Wcat, bcat, qb, kb, vb, sb, N);

    node_kernel<<<(N + 3) / 4, 256, 0, stream>>>(qb, kb, vb, sb, srclist, startv, counts,
                                                 Wg, bg, lnw, lnb, pa, out, N, E);
}

// Round 6
// 353.346 us; speedup vs baseline: 1.3384x; 1.1634x over previous
//
#include <hip/hip_runtime.h>
#include <math.h>

// GraphAttnModel: N=50000, E=800000, F=256, H=4, D=64.
// Pipeline:
//   1) prep: convert feat+weights+biases to bf16 ws copies, zero CSR counters
//   2) CSR-by-dst build (count / alloc / fill-src), scan-free wave atomics
//   3) fused bf16 MFMA GEMM (128x256 tile, global_load_lds staging).
//      Swapped-operand MFMA -> lane holds 4 consecutive cols of one row.
//      q,v outputs stored FP8 e4m3 (halves the node-phase gather bytes);
//      k,skip stored bf16.
//   4) one wave per dst node: no-max softmax edge attention (logits |e|<~1;
//      softmax shift-invariant) + gate + LayerNorm + PReLU, f32 output.

typedef __attribute__((ext_vector_type(8))) short short8;   // 8 bf16 = 4 VGPRs
typedef __attribute__((ext_vector_type(4))) float floatx4;  // MFMA acc
typedef __attribute__((ext_vector_type(2))) float floatx2;  // fp8 decode pair
typedef __attribute__((address_space(3))) void lds_void;
typedef __attribute__((address_space(1))) const void gbl_void;

__device__ inline unsigned short f2bf(float x) {            // RNE f32->bf16
    unsigned int u = __float_as_uint(x);
    u = (u + 0x7fffu + ((u >> 16) & 1u)) >> 16;
    return (unsigned short)u;
}
__device__ inline float bf2f(unsigned short u) {
    return __uint_as_float(((unsigned int)u) << 16);
}

// ---------------- prep: converts + CSR zero ----------------
__global__ void prep_kernel(const float* __restrict__ f, ushort* __restrict__ fb,
                            int n_elems, int total_pad,
                            const float* __restrict__ Wq, const float* __restrict__ Wk,
                            const float* __restrict__ Wv, const float* __restrict__ Wsk,
                            const float* __restrict__ bq, const float* __restrict__ bk,
                            const float* __restrict__ bv, const float* __restrict__ bsk,
                            ushort* __restrict__ Wcat, float* __restrict__ bcat,
                            int* __restrict__ counts, int* __restrict__ cursor, int n)
{
    int g = blockIdx.x * blockDim.x + threadIdx.x;
    int featQ = total_pad >> 2;               // feat quads
    if (g < featQ) {
        int i = g * 4;
        float4 v = (i < n_elems) ? *(const float4*)(f + i) : make_float4(0.f, 0.f, 0.f, 0.f);
        ushort4 u;
        u.x = f2bf(v.x); u.y = f2bf(v.y); u.z = f2bf(v.z); u.w = f2bf(v.w);
        *(ushort4*)(fb + i) = u;
        return;
    }
    int g2 = g - featQ;
    if (g2 < 65536) {                         // weights: 262144/4
        int i = g2 * 4;
        int mat = i >> 16;
        int rem = i & 65535;
        const float* W = (mat == 0) ? Wq : (mat == 1) ? Wk : (mat == 2) ? Wv : Wsk;
        float4 v = *(const float4*)(W + rem);
        ushort4 u;
        u.x = f2bf(v.x); u.y = f2bf(v.y); u.z = f2bf(v.z); u.w = f2bf(v.w);
        *(ushort4*)(Wcat + i) = u;
        return;
    }
    int g3 = g2 - 65536;
    if (g3 < 256) {                           // biases: 1024/4
        int o = g3 * 4;
        int mat = o >> 8;
        const float* b = (mat == 0) ? bq : (mat == 1) ? bk : (mat == 2) ? bv : bsk;
        *(float4*)(bcat + o) = *(const float4*)(b + (o & 255));
        return;
    }
    int g4 = g3 - 256;
    if (g4 < n) counts[g4] = 0;
    if (g4 == 0) *cursor = 0;
}

// ---------------- CSR build ----------------

__global__ void count_kernel(const int* __restrict__ dst, int* counts, int e) {
    int i = blockIdx.x * blockDim.x + threadIdx.x;
    if (i < e) atomicAdd(&counts[dst[i]], 1);
}

__global__ void alloc_kernel(const int* __restrict__ counts, int* start, int* cur,
                             int* cursor, int n) {
    int i = blockIdx.x * blockDim.x + threadIdx.x;
    int lane = threadIdx.x & 63;
    int c = (i < n) ? counts[i] : 0;
    int incl = c;
#pragma unroll
    for (int d = 1; d < 64; d <<= 1) {
        int t = __shfl_up(incl, d);
        if (lane >= d) incl += t;
    }
    int waveTot = __shfl(incl, 63);
    int base = 0;
    if (lane == 63) base = atomicAdd(cursor, waveTot);
    base = __shfl(base, 63);
    if (i < n) {
        int s = base + incl - c;
        start[i] = s;
        cur[i] = s;
    }
}

__global__ void fill_kernel(const int* __restrict__ dst, const int* __restrict__ src,
                            int* cur, int* srclist, int e) {
    int i = blockIdx.x * blockDim.x + threadIdx.x;
    if (i < e) {
        int pos = atomicAdd(&cur[dst[i]], 1);
        srclist[pos] = src[i];
    }
}

// ---------------- fused bf16 MFMA projection GEMM ----------------
// C[m][o] = sum_k featb[m][k] * Wcat[o][k] + bcat[o],  m<50048(pad), o<1024.
// Block: 512 thr = 8 waves; tile 128m x 256n; wave tile 64x64 (4x4 MFMA).
// blockIdx.x (fastest-varying) selects output matrix -> 4 concurrent blocks
// share the same featb A-tile (L2/L3 hits). Swapped-operand MFMA:
// D[n_local][m_local], m_local=lane&15 (row), n_local=(lane>>4)*4+reg
// (4 consecutive cols). q (y=0) and v (y=2) written fp8 e4m3; k,skip bf16.
__global__ __launch_bounds__(512) void mfma_gemm(
    const ushort* __restrict__ featb, const ushort* __restrict__ Wcat,
    const float* __restrict__ bcat,
    unsigned char* __restrict__ q8, ushort* __restrict__ kb,
    unsigned char* __restrict__ v8, ushort* __restrict__ sb, int n)
{
    __shared__ ushort At[128 * 32];  // 8 KB
    __shared__ ushort Bt[256 * 32];  // 16 KB
    int tid = threadIdx.x;
    int lane = tid & 63;
    int wv = tid >> 6;               // 0..7
    int ysel = blockIdx.x;           // 0..3: q,k,v,skip
    int mBase = blockIdx.y * 128;
    int nBlk = ysel * 256;
    int mQuad = (wv & 1) * 64;
    int nQuad = (wv >> 1) * 64;

    floatx4 zero = {0.f, 0.f, 0.f, 0.f};
    floatx4 acc[4][4];               // [m-tile][n-tile]
#pragma unroll
    for (int i = 0; i < 4; ++i)
#pragma unroll
        for (int j = 0; j < 4; ++j) acc[i][j] = zero;

    int rsel = lane & 15;
    int ksel = (lane >> 4) * 8;
    int lrow = lane >> 2;            // 0..15
    int lcol = (lane & 3) * 8;       // ushort offset 0,8,16,24

    for (int k0 = 0; k0 < 256; k0 += 32) {
        {
            int row = 16 * wv + lrow;
            const ushort* gp = featb + (size_t)(mBase + row) * 256 + k0 + lcol;
            __builtin_amdgcn_global_load_lds((gbl_void*)gp, (lds_void*)&At[16 * wv * 32], 16, 0, 0);
        }
#pragma unroll
        for (int r = 0; r < 2; ++r) {
            int row = 32 * wv + 16 * r + lrow;
            const ushort* gp = Wcat + (size_t)(nBlk + row) * 256 + k0 + lcol;
            __builtin_amdgcn_global_load_lds((gbl_void*)gp, (lds_void*)&Bt[(32 * wv + 16 * r) * 32], 16, 0, 0);
        }
        __syncthreads();
        short8 af[4], bf[4];
#pragma unroll
        for (int i = 0; i < 4; ++i)
            af[i] = *(const short8*)&At[(mQuad + 16 * i + rsel) * 32 + ksel];
#pragma unroll
        for (int j = 0; j < 4; ++j)
            bf[j] = *(const short8*)&Bt[(nQuad + 16 * j + rsel) * 32 + ksel];
#pragma unroll
        for (int i = 0; i < 4; ++i)
#pragma unroll
            for (int j = 0; j < 4; ++j)
                acc[i][j] = __builtin_amdgcn_mfma_f32_16x16x32_bf16(bf[j], af[i], acc[i][j], 0, 0, 0);
        __syncthreads();
    }

    int rowq4 = (lane >> 4) * 4;     // n_local base of this lane's 4 cols
    float4 bias[4];
#pragma unroll
    for (int nt = 0; nt < 4; ++nt)
        bias[nt] = *(const float4*)(bcat + nBlk + nQuad + 16 * nt + rowq4);

    if (ysel == 0 || ysel == 2) {            // fp8 outputs (q / v)
        unsigned char* outp = (ysel == 0) ? q8 : v8;
#pragma unroll
        for (int mt = 0; mt < 4; ++mt) {
            int m = mBase + mQuad + 16 * mt + (lane & 15);
            if (m < n) {
                unsigned char* rowp = outp + (size_t)m * 256 + nQuad + rowq4;
#pragma unroll
                for (int nt = 0; nt < 4; ++nt) {
                    int pk = __builtin_amdgcn_cvt_pk_fp8_f32(
                        acc[mt][nt][0] + bias[nt].x, acc[mt][nt][1] + bias[nt].y, 0, false);
                    pk = __builtin_amdgcn_cvt_pk_fp8_f32(
                        acc[mt][nt][2] + bias[nt].z, acc[mt][nt][3] + bias[nt].w, pk, true);
                    *(int*)(rowp + 16 * nt) = pk;
                }
            }
        }
    } else {                                  // bf16 outputs (k / skip)
        ushort* outp = (ysel == 1) ? kb : sb;
#pragma unroll
        for (int mt = 0; mt < 4; ++mt) {
            int m = mBase + mQuad + 16 * mt + (lane & 15);
            if (m < n) {
                ushort* rowp = outp + (size_t)m * 256 + nQuad + rowq4;
#pragma unroll
                for (int nt = 0; nt < 4; ++nt) {
                    uint lo = (uint)f2bf(acc[mt][nt][0] + bias[nt].x)
                            | ((uint)f2bf(acc[mt][nt][1] + bias[nt].y) << 16);
                    uint hi = (uint)f2bf(acc[mt][nt][2] + bias[nt].z)
                            | ((uint)f2bf(acc[mt][nt][3] + bias[nt].w) << 16);
                    *(uint2*)(rowp + 16 * nt) = make_uint2(lo, hi);
                }
            }
        }
    }
}

// ---------------- per-node attention + epilogue ----------------
// One wave per dst node; 16-lane group g = head g; lane owns 4 consecutive
// features. q/v gathers are fp8 (4 B/lane/row). Softmax without max
// subtraction (shift-invariant; logits tiny). 2-edge unroll.
__global__ __launch_bounds__(256) void node_kernel(
    const unsigned char* __restrict__ q8, const ushort* __restrict__ kb,
    const unsigned char* __restrict__ v8, const ushort* __restrict__ sbuf,
    const int* __restrict__ srclist, const int* __restrict__ start,
    const int* __restrict__ counts,
    const float* __restrict__ Wg, const float* __restrict__ bg,
    const float* __restrict__ lnw, const float* __restrict__ lnb,
    const float* __restrict__ pa,
    float* __restrict__ out, int n, int E)
{
    int wvi = threadIdx.x >> 6;
    int lane = threadIdx.x & 63;
    int node = blockIdx.x * 4 + wvi;
    if (node >= n) return;

    int f0 = (lane >> 4) * 64 + (lane & 15) * 4;

    ushort4 ku = *(const ushort4*)(kb + (size_t)node * 256 + f0);
    float k0 = bf2f(ku.x), k1 = bf2f(ku.y), k2 = bf2f(ku.z), k3 = bf2f(ku.w);

    float lA = 0.f, a0 = 0.f, a1 = 0.f, a2 = 0.f, a3 = 0.f;
    float lB = 0.f, b0 = 0.f, b1 = 0.f, b2 = 0.f, b3 = 0.f;

    int sidx = start[node], cnt = counts[node];

    for (int base = 0; base < cnt; base += 64) {
        int m = min(64, cnt - base);
        int gi = sidx + base + lane;
        int batch = srclist[min(gi, E - 1)];
        int j = 0;
        for (; j + 1 < m; j += 2) {
            int s0i = __shfl(batch, j);
            int s1i = __shfl(batch, j + 1);
            uint qw0 = *(const uint*)(q8 + (size_t)s0i * 256 + f0);
            uint vw0 = *(const uint*)(v8 + (size_t)s0i * 256 + f0);
            uint qw1 = *(const uint*)(q8 + (size_t)s1i * 256 + f0);
            uint vw1 = *(const uint*)(v8 + (size_t)s1i * 256 + f0);
            floatx2 ql0 = __builtin_amdgcn_cvt_pk_f32_fp8(qw0, false);
            floatx2 qh0 = __builtin_amdgcn_cvt_pk_f32_fp8(qw0, true);
            floatx2 ql1 = __builtin_amdgcn_cvt_pk_f32_fp8(qw1, false);
            floatx2 qh1 = __builtin_amdgcn_cvt_pk_f32_fp8(qw1, true);
            float p0 = ql0[0] * k0 + ql0[1] * k1 + qh0[0] * k2 + qh0[1] * k3;
            float p1 = ql1[0] * k0 + ql1[1] * k1 + qh1[0] * k2 + qh1[1] * k3;
            p0 += __shfl_xor(p0, 1);  p1 += __shfl_xor(p1, 1);
            p0 += __shfl_xor(p0, 2);  p1 += __shfl_xor(p1, 2);
            p0 += __shfl_xor(p0, 4);  p1 += __shfl_xor(p1, 4);
            p0 += __shfl_xor(p0, 8);  p1 += __shfl_xor(p1, 8);
            float w0 = __expf(p0 * 0.125f);
            float w1 = __expf(p1 * 0.125f);
            floatx2 vl0 = __builtin_amdgcn_cvt_pk_f32_fp8(vw0, false);
            floatx2 vh0 = __builtin_amdgcn_cvt_pk_f32_fp8(vw0, true);
            floatx2 vl1 = __builtin_amdgcn_cvt_pk_f32_fp8(vw1, false);
            floatx2 vh1 = __builtin_amdgcn_cvt_pk_f32_fp8(vw1, true);
            lA += w0;
            a0 += w0 * vl0[0]; a1 += w0 * vl0[1];
            a2 += w0 * vh0[0]; a3 += w0 * vh0[1];
            lB += w1;
            b0 += w1 * vl1[0]; b1 += w1 * vl1[1];
            b2 += w1 * vh1[0]; b3 += w1 * vh1[1];
        }
        if (j < m) {
            int s0i = __shfl(batch, j);
            uint qw0 = *(const uint*)(q8 + (size_t)s0i * 256 + f0);
            uint vw0 = *(const uint*)(v8 + (size_t)s0i * 256 + f0);
            floatx2 ql0 = __builtin_amdgcn_cvt_pk_f32_fp8(qw0, false);
            floatx2 qh0 = __builtin_amdgcn_cvt_pk_f32_fp8(qw0, true);
            float p0 = ql0[0] * k0 + ql0[1] * k1 + qh0[0] * k2 + qh0[1] * k3;
            p0 += __shfl_xor(p0, 1);
            p0 += __shfl_xor(p0, 2);
            p0 += __shfl_xor(p0, 4);
            p0 += __shfl_xor(p0, 8);
            float w0 = __expf(p0 * 0.125f);
            floatx2 vl0 = __builtin_amdgcn_cvt_pk_f32_fp8(vw0, false);
            floatx2 vh0 = __builtin_amdgcn_cvt_pk_f32_fp8(vw0, true);
            lA += w0;
            a0 += w0 * vl0[0]; a1 += w0 * vl0[1];
            a2 += w0 * vh0[0]; a3 += w0 * vh0[1];
        }
    }
    float lsum = lA + lB;
    float inv = (lsum > 0.f) ? 1.f / lsum : 0.f;
    float r0 = (a0 + b0) * inv, r1 = (a1 + b1) * inv;
    float r2 = (a2 + b2) * inv, r3 = (a3 + b3) * inv;

    ushort4 su = *(const ushort4*)(sbuf + (size_t)node * 256 + f0);
    float s0 = bf2f(su.x), s1 = bf2f(su.y), s2 = bf2f(su.z), s3 = bf2f(su.w);

    float4 w0v = *(const float4*)(Wg + f0);
    float4 w1v = *(const float4*)(Wg + 256 + f0);
    float4 w2v = *(const float4*)(Wg + 512 + f0);
    float z = w0v.x * s0 + w0v.y * s1 + w0v.z * s2 + w0v.w * s3
            + w1v.x * r0 + w1v.y * r1 + w1v.z * r2 + w1v.w * r3
            + w2v.x * (s0 - r0) + w2v.y * (s1 - r1) + w2v.z * (s2 - r2) + w2v.w * (s3 - r3);
#pragma unroll
    for (int d = 32; d >= 1; d >>= 1) z += __shfl_xor(z, d);
    z += bg[0];
    float g = 1.f / (1.f + __expf(-z));

    float y0 = g * s0 + (1.f - g) * r0;
    float y1 = g * s1 + (1.f - g) * r1;
    float y2 = g * s2 + (1.f - g) * r2;
    float y3 = g * s3 + (1.f - g) * r3;

    float sum = y0 + y1 + y2 + y3;
#pragma unroll
    for (int d = 32; d >= 1; d >>= 1) sum += __shfl_xor(sum, d);
    float mu = sum * (1.f / 256.f);
    float d0 = y0 - mu, d1 = y1 - mu, d2 = y2 - mu, d3 = y3 - mu;
    float sq = d0 * d0 + d1 * d1 + d2 * d2 + d3 * d3;
#pragma unroll
    for (int d = 32; d >= 1; d >>= 1) sq += __shfl_xor(sq, d);
    float rstd = rsqrtf(sq * (1.f / 256.f) + 1e-5f);

    float4 lw = *(const float4*)(lnw + f0);
    float4 lb = *(const float4*)(lnb + f0);
    float o0 = d0 * rstd * lw.x + lb.x;
    float o1 = d1 * rstd * lw.y + lb.y;
    float o2 = d2 * rstd * lw.z + lb.z;
    float o3 = d3 * rstd * lw.w + lb.w;
    float ap = pa[0];
    o0 = (o0 >= 0.f) ? o0 : ap * o0;
    o1 = (o1 >= 0.f) ? o1 : ap * o1;
    o2 = (o2 >= 0.f) ? o2 : ap * o2;
    o3 = (o3 >= 0.f) ? o3 : ap * o3;

    *(float4*)(out + (size_t)node * 256 + f0) = make_float4(o0, o1, o2, o3);
}

// ---------------- launch ----------------

extern "C" void kernel_launch(void* const* d_in, const int* in_sizes, int n_in,
                              void* d_out, int out_size, void* d_ws, size_t ws_size,
                              hipStream_t stream)
{
    const float* feat = (const float*)d_in[0];
    const int* src    = (const int*)d_in[1];
    const int* dst    = (const int*)d_in[2];
    const float* Wq   = (const float*)d_in[3];
    const float* bq   = (const float*)d_in[4];
    const float* Wk   = (const float*)d_in[5];
    const float* bk   = (const float*)d_in[6];
    const float* Wv   = (const float*)d_in[7];
    const float* bv   = (const float*)d_in[8];
    const float* Wsk  = (const float*)d_in[9];
    const float* bsk  = (const float*)d_in[10];
    const float* Wg   = (const float*)d_in[11];
    const float* bg   = (const float*)d_in[12];
    const float* lnw  = (const float*)d_in[13];
    const float* lnb  = (const float*)d_in[14];
    const float* pa   = (const float*)d_in[15];

    int N = in_sizes[0] / 256;
    int E = in_sizes[1];
    float* out = (float*)d_out;

    int Mtiles = (N + 127) / 128;
    int Npad = Mtiles * 128;

    char* ws = (char*)d_ws;
    size_t off = 0;
    auto alloc = [&](size_t bytes) { char* p = ws + off; off = (off + bytes + 255) & ~(size_t)255; return p; };
    ushort* featb      = (ushort*)alloc((size_t)Npad * 256 * 2);
    ushort* Wcat       = (ushort*)alloc(1024 * 256 * 2);
    float*  bcat       = (float*) alloc(1024 * 4);
    unsigned char* q8  = (unsigned char*)alloc((size_t)N * 256);
    unsigned char* v8  = (unsigned char*)alloc((size_t)N * 256);
    ushort* kb         = (ushort*)alloc((size_t)N * 256 * 2);
    ushort* sb         = (ushort*)alloc((size_t)N * 256 * 2);
    int* counts        = (int*)alloc((size_t)N * 4);
    int* startv        = (int*)alloc((size_t)N * 4);
    int* cur           = (int*)alloc((size_t)N * 4);
    int* cursor        = (int*)alloc(4);
    int* srclist       = (int*)alloc((size_t)E * 4);

    int totPad = Npad * 256;
    int prepThreads = totPad / 4 + 65536 + 256 + N;
    prep_kernel<<<(prepThreads + 255) / 256, 256, 0, stream>>>(
        feat, featb, N * 256, totPad, Wq, Wk, Wv, Wsk, bq, bk, bv, bsk,
        Wcat, bcat, counts, cursor, N);

    count_kernel<<<(E + 255) / 256, 256, 0, stream>>>(dst, counts, E);
    alloc_kernel<<<(N + 255) / 256, 256, 0, stream>>>(counts, startv, cur, cursor, N);
    fill_kernel<<<(E + 255) / 256, 256, 0, stream>>>(dst, src, cur, srclist, E);

    dim3 gg(4, Mtiles);
    mfma_gemm<<<gg, 512, 0, stream>>>(featb, Wcat, bcat, q8, kb, v8, sb, N);

    node_kernel<<<(N + 3) / 4, 256, 0, stream>>>(q8, kb, v8, sb, srclist, startv, counts,
                                                 Wg, bg, lnw, lnb, pa, out, N, E);
}